// Round 1
// baseline (42.535 us; speedup 1.0000x reference)
//
#include <hip/hip_runtime.h>
#include <math.h>

// Problem constants (match reference)
#define BATCH 4
#define LSEQ  4096
#define DCH   512
#define NST   16
#define TCH   64                 // chunk length along L
#define CCH   (LSEQ / TCH)       // 64 chunks

// ---------------------------------------------------------------------------
// Kernel 1: per-(b,d,chunk) local scan with h0 = 0; write final chunk state.
// Thread id layout: id = (b*CCH + c)*DCH + d  (d fastest -> coalesced x reads)
// ---------------------------------------------------------------------------
__global__ __launch_bounds__(256) void k_local_scan(
    const float* __restrict__ x, const float* __restrict__ A,
    const float* __restrict__ Bm, const float* __restrict__ delta,
    float* __restrict__ states)
{
    int id = blockIdx.x * 256 + threadIdx.x;
    int d  = id % DCH;
    int c  = (id / DCH) % CCH;
    int b  = id / (DCH * CCH);

    float dl = delta[d];
    float dA[NST], dB[NST], h[NST];
#pragma unroll
    for (int n = 0; n < NST; ++n) {
        dA[n] = expf(dl * A[d * NST + n]);
        dB[n] = dl * Bm[d * NST + n];
        h[n]  = 0.f;
    }

    const float* xp = x + ((size_t)b * LSEQ + (size_t)c * TCH) * DCH + d;
#pragma unroll 4
    for (int t = 0; t < TCH; ++t) {
        float xv = xp[(size_t)t * DCH];
#pragma unroll
        for (int n = 0; n < NST; ++n)
            h[n] = fmaf(h[n], dA[n], xv * dB[n]);
    }

    float4* sp = (float4*)(states + (size_t)id * NST);
    sp[0] = make_float4(h[0],  h[1],  h[2],  h[3]);
    sp[1] = make_float4(h[4],  h[5],  h[6],  h[7]);
    sp[2] = make_float4(h[8],  h[9],  h[10], h[11]);
    sp[3] = make_float4(h[12], h[13], h[14], h[15]);
}

// ---------------------------------------------------------------------------
// Kernel 2: per-(b,d,n) serial exclusive scan over chunk states (in place).
// states[idx] becomes the ENTRY state of chunk c; decay factor is dA^TCH
// via repeated squaring of the rounded dA (matches sequential semantics).
// ---------------------------------------------------------------------------
__global__ __launch_bounds__(256) void k_chunk_scan(
    const float* __restrict__ A, const float* __restrict__ delta,
    float* __restrict__ states)
{
    int j = blockIdx.x * 256 + threadIdx.x;   // (b, d, n), n fastest
    int n = j % NST;
    int d = (j / NST) % DCH;
    int b = j / (NST * DCH);

    float dA = expf(delta[d] * A[d * NST + n]);
    // dA^TCH, TCH = 64 = 2^6
    float dAT = dA;
#pragma unroll
    for (int k = 0; k < 6; ++k) dAT *= dAT;

    float h = 0.f;
    for (int c = 0; c < CCH; ++c) {
        size_t idx = (((size_t)b * CCH + c) * DCH + d) * NST + n;
        float s = states[idx];
        states[idx] = h;            // exclusive prefix -> entry state
        h = fmaf(h, dAT, s);
    }
}

// ---------------------------------------------------------------------------
// Kernel 3: per-(b,d,chunk) replay from entry state, emit y = sum_n h[n].
// ---------------------------------------------------------------------------
__global__ __launch_bounds__(256) void k_fixup(
    const float* __restrict__ x, const float* __restrict__ A,
    const float* __restrict__ Bm, const float* __restrict__ delta,
    const float* __restrict__ states, float* __restrict__ y)
{
    int id = blockIdx.x * 256 + threadIdx.x;
    int d  = id % DCH;
    int c  = (id / DCH) % CCH;
    int b  = id / (DCH * CCH);

    float dl = delta[d];
    float dA[NST], dB[NST], h[NST];

    const float4* sp = (const float4*)(states + (size_t)id * NST);
    float4 s0 = sp[0], s1 = sp[1], s2 = sp[2], s3 = sp[3];
    h[0]=s0.x; h[1]=s0.y; h[2]=s0.z; h[3]=s0.w;
    h[4]=s1.x; h[5]=s1.y; h[6]=s1.z; h[7]=s1.w;
    h[8]=s2.x; h[9]=s2.y; h[10]=s2.z; h[11]=s2.w;
    h[12]=s3.x; h[13]=s3.y; h[14]=s3.z; h[15]=s3.w;

#pragma unroll
    for (int n = 0; n < NST; ++n) {
        dA[n] = expf(dl * A[d * NST + n]);
        dB[n] = dl * Bm[d * NST + n];
    }

    size_t off = ((size_t)b * LSEQ + (size_t)c * TCH) * DCH + d;
    const float* xp = x + off;
    float*       yp = y + off;

#pragma unroll 4
    for (int t = 0; t < TCH; ++t) {
        float xv = xp[(size_t)t * DCH];
#pragma unroll
        for (int n = 0; n < NST; ++n)
            h[n] = fmaf(h[n], dA[n], xv * dB[n]);
        // pairwise tree sum of 16 states
        float s01 = (h[0]+h[1])   + (h[2]+h[3]);
        float s23 = (h[4]+h[5])   + (h[6]+h[7]);
        float s45 = (h[8]+h[9])   + (h[10]+h[11]);
        float s67 = (h[12]+h[13]) + (h[14]+h[15]);
        yp[(size_t)t * DCH] = (s01 + s23) + (s45 + s67);
    }
}

extern "C" void kernel_launch(void* const* d_in, const int* in_sizes, int n_in,
                              void* d_out, int out_size, void* d_ws, size_t ws_size,
                              hipStream_t stream) {
    const float* x     = (const float*)d_in[0];   // (B, L, D)
    const float* A     = (const float*)d_in[1];   // (D, N)
    const float* Bm    = (const float*)d_in[2];   // (D, N)
    const float* delta = (const float*)d_in[3];   // (D,)
    float*       y     = (float*)d_out;           // (B, L, D)
    float*       states = (float*)d_ws;           // B*C*D*N floats = 8 MiB

    const int n_chunk_threads = BATCH * DCH * CCH;   // 131072
    const int n_state_threads = BATCH * DCH * NST;   // 32768

    k_local_scan<<<n_chunk_threads / 256, 256, 0, stream>>>(x, A, Bm, delta, states);
    k_chunk_scan<<<n_state_threads / 256, 256, 0, stream>>>(A, delta, states);
    k_fixup<<<n_chunk_threads / 256, 256, 0, stream>>>(x, A, Bm, delta, states, y);
}

// Round 4
// 35.882 us; speedup vs baseline: 1.1854x; 1.1854x over previous
//
#include <hip/hip_runtime.h>
#include <math.h>

// Problem constants (match reference)
#define BATCH 4
#define LSEQ  4096
#define DCH   512
#define NST   16
#define TCH   64                 // chunk length along L
#define CCH   (LSEQ / TCH)       // 64 chunks

// ---------------------------------------------------------------------------
// Kernel 1: per-(b,d,chunk) local scan with h0 = 0; write final chunk state.
// Thread id = (b*CCH + c)*DCH + d  (d fastest -> coalesced x reads).
// states layout: [b][c][n][d] -> state stores lane-coalesced per n.
// ---------------------------------------------------------------------------
__global__ __launch_bounds__(256) void k_local_scan(
    const float* __restrict__ x, const float* __restrict__ A,
    const float* __restrict__ Bm, const float* __restrict__ delta,
    float* __restrict__ states)
{
    int id = blockIdx.x * 256 + threadIdx.x;
    int d  = id % DCH;
    int c  = (id / DCH) % CCH;
    int b  = id / (DCH * CCH);

    float dl = delta[d];
    float dA[NST], dB[NST], h[NST];
#pragma unroll
    for (int n = 0; n < NST; ++n) {
        dA[n] = expf(dl * A[d * NST + n]);
        dB[n] = dl * Bm[d * NST + n];
        h[n]  = 0.f;
    }

    const float* xp = x + ((size_t)b * LSEQ + (size_t)c * TCH) * DCH + d;
#pragma unroll 8
    for (int t = 0; t < TCH; ++t) {
        float xv = xp[(size_t)t * DCH];
#pragma unroll
        for (int n = 0; n < NST; ++n)
            h[n] = fmaf(h[n], dA[n], xv * dB[n]);
    }

#pragma unroll
    for (int n = 0; n < NST; ++n)
        states[(((size_t)b * CCH + c) * NST + n) * DCH + d] = h[n];
}

// ---------------------------------------------------------------------------
// Kernel 2: per-(b,n,d) serial exclusive scan over chunk states, in place.
// Thread id: d fastest -> every load/store across the wave is coalesced;
// the 64 chunk addresses are independent -> unroll lets them pipeline.
// ---------------------------------------------------------------------------
__global__ __launch_bounds__(256) void k_chunk_scan(
    const float* __restrict__ A, const float* __restrict__ delta,
    float* __restrict__ states)
{
    int j = blockIdx.x * 256 + threadIdx.x;   // (b, n, d), d fastest
    int d = j % DCH;
    int n = (j / DCH) % NST;
    int b = j / (DCH * NST);

    float dAv = expf(delta[d] * A[d * NST + n]);
    float dAT = dAv;                          // dA^64 via 6 squarings
#pragma unroll
    for (int k = 0; k < 6; ++k) dAT *= dAT;

    float hp = 0.f;
#pragma unroll 8
    for (int c = 0; c < CCH; ++c) {
        size_t idx = (((size_t)b * CCH + c) * NST + n) * DCH + d;
        float s = states[idx];
        states[idx] = hp;                     // exclusive prefix -> entry state
        hp = fmaf(hp, dAT, s);
    }
}

// ---------------------------------------------------------------------------
// Kernel 3: per-(b,d,chunk) replay from entry state, emit y = sum_n h[n].
// x re-read is expected to hit L3 (32 MiB, streamed by K1 moments earlier).
// ---------------------------------------------------------------------------
__global__ __launch_bounds__(256) void k_fixup(
    const float* __restrict__ x, const float* __restrict__ A,
    const float* __restrict__ Bm, const float* __restrict__ delta,
    const float* __restrict__ states, float* __restrict__ y)
{
    int id = blockIdx.x * 256 + threadIdx.x;
    int d  = id % DCH;
    int c  = (id / DCH) % CCH;
    int b  = id / (DCH * CCH);

    float dl = delta[d];
    float dA[NST], dB[NST], h[NST];

#pragma unroll
    for (int n = 0; n < NST; ++n) {
        dA[n] = expf(dl * A[d * NST + n]);
        dB[n] = dl * Bm[d * NST + n];
        h[n]  = states[(((size_t)b * CCH + c) * NST + n) * DCH + d];
    }

    size_t off = ((size_t)b * LSEQ + (size_t)c * TCH) * DCH + d;
    const float* xp = x + off;
    float*       yp = y + off;

#pragma unroll 8
    for (int t = 0; t < TCH; ++t) {
        float xv = xp[(size_t)t * DCH];
#pragma unroll
        for (int n = 0; n < NST; ++n)
            h[n] = fmaf(h[n], dA[n], xv * dB[n]);
        float s01 = (h[0]  + h[1])  + (h[2]  + h[3]);
        float s23 = (h[4]  + h[5])  + (h[6]  + h[7]);
        float s45 = (h[8]  + h[9])  + (h[10] + h[11]);
        float s67 = (h[12] + h[13]) + (h[14] + h[15]);
        yp[(size_t)t * DCH] = (s01 + s23) + (s45 + s67);
    }
}

extern "C" void kernel_launch(void* const* d_in, const int* in_sizes, int n_in,
                              void* d_out, int out_size, void* d_ws, size_t ws_size,
                              hipStream_t stream) {
    const float* x     = (const float*)d_in[0];   // (B, L, D)
    const float* A     = (const float*)d_in[1];   // (D, N)
    const float* Bm    = (const float*)d_in[2];   // (D, N)
    const float* delta = (const float*)d_in[3];   // (D,)
    float*       y     = (float*)d_out;           // (B, L, D)
    float*       states = (float*)d_ws;           // B*C*N*D floats = 8 MiB

    const int n_chunk_threads = BATCH * DCH * CCH;   // 131072
    const int n_state_threads = BATCH * DCH * NST;   // 32768

    k_local_scan<<<n_chunk_threads / 256, 256, 0, stream>>>(x, A, Bm, delta, states);
    k_chunk_scan<<<n_state_threads / 256, 256, 0, stream>>>(A, delta, states);
    k_fixup<<<n_chunk_threads / 256, 256, 0, stream>>>(x, A, Bm, delta, states, y);
}